// Round 4
// baseline (1694.474 us; speedup 1.0000x reference)
//
#include <hip/hip_runtime.h>
#include <math.h>

#define B_    16
#define C_    384
#define L_    4096
#define K_    4096
#define KH_   32
#define NL_   3
#define HID_  384
#define NFFT  8192
#define OMEGA_ 976.0f

// LDS swizzle: XOR bit4 of the float index with bit7 -> stage strides stay
// near-conflict-free and 16-aligned chunks remain contiguous. Even addresses
// keep pair-contiguity (bit0 untouched), so float2/float4 accesses are safe.
#define SWZ(a) ((a) ^ ((((a) >> 7) & 1) << 4))

// ---------------------------------------------------------------------------
// Twiddles: tw[t] = exp(-2*pi*i*t/NFFT), t = 0..NFFT-1
// ---------------------------------------------------------------------------
__global__ __launch_bounds__(256) void gen_tw(float2* __restrict__ tw) {
  int j = blockIdx.x * 256 + threadIdx.x;
  if (j < NFFT) {
    double a = -2.0 * 3.14159265358979323846 * (double)j / (double)NFFT;
    double s, c;
    sincos(a, &s, &c);
    tw[j] = make_float2((float)c, (float)s);
  }
}

// ------------------------- scalar complex helpers --------------------------
__device__ __forceinline__ float2 cadd(float2 a, float2 b) { return make_float2(a.x + b.x, a.y + b.y); }
__device__ __forceinline__ float2 csub(float2 a, float2 b) { return make_float2(a.x - b.x, a.y - b.y); }
__device__ __forceinline__ float2 cmul(float2 a, float2 b) { return make_float2(a.x * b.x - a.y * b.y, a.x * b.y + a.y * b.x); }
__device__ __forceinline__ float2 cmulc(float2 a, float2 b) { // a * conj(b)
  return make_float2(a.x * b.x + a.y * b.y, a.y * b.x - a.x * b.y);
}

// ------------------------- packed-pair complex (2 butterflies) -------------
struct cp { float2 re, im; };
__device__ __forceinline__ float2 f2a(float2 a, float2 b) { return make_float2(a.x + b.x, a.y + b.y); }
__device__ __forceinline__ float2 f2s(float2 a, float2 b) { return make_float2(a.x - b.x, a.y - b.y); }
__device__ __forceinline__ float2 f2m(float2 a, float2 b) { return make_float2(a.x * b.x, a.y * b.y); }
__device__ __forceinline__ float2 f2k(float2 a, float s)  { return make_float2(a.x * s, a.y * s); }
__device__ __forceinline__ cp cpadd(cp a, cp b) { return {f2a(a.re, b.re), f2a(a.im, b.im)}; }
__device__ __forceinline__ cp cpsub(cp a, cp b) { return {f2s(a.re, b.re), f2s(a.im, b.im)}; }
// a * (wr + i*wi), per-element twiddles
__device__ __forceinline__ cp cpmul(cp a, float2 wr, float2 wi) {
  return { f2s(f2m(a.re, wr), f2m(a.im, wi)), f2a(f2m(a.re, wi), f2m(a.im, wr)) };
}
__device__ __forceinline__ cp cpmulc(cp a, float2 wr, float2 wi) { // a * conj(w)
  return { f2a(f2m(a.re, wr), f2m(a.im, wi)), f2s(f2m(a.im, wr), f2m(a.re, wi)) };
}

// 8-point DFT on packed pairs (forward, W8 = exp(-i*pi/4)), in place
__device__ __forceinline__ void dft8p_fwd(cp* a) {
  const float c = 0.70710678118654752f;
  cp t0 = cpadd(a[0], a[4]), t1 = cpsub(a[0], a[4]);
  cp t2 = cpadd(a[2], a[6]), t3 = cpsub(a[2], a[6]);
  cp t4 = cpadd(a[1], a[5]), t5 = cpsub(a[1], a[5]);
  cp t6 = cpadd(a[3], a[7]), t7 = cpsub(a[3], a[7]);
  cp E0 = cpadd(t0, t2), E2 = cpsub(t0, t2);
  cp E1 = { f2a(t1.re, t3.im), f2s(t1.im, t3.re) };   // t1 - i*t3
  cp E3 = { f2s(t1.re, t3.im), f2a(t1.im, t3.re) };   // t1 + i*t3
  cp O0 = cpadd(t4, t6), O2 = cpsub(t4, t6);
  cp O1 = { f2a(t5.re, t7.im), f2s(t5.im, t7.re) };
  cp O3 = { f2s(t5.re, t7.im), f2a(t5.im, t7.re) };
  cp O1w = { f2k(f2a(O1.re, O1.im), c), f2k(f2s(O1.im, O1.re), c) };    // *W8^1
  cp O2w = { O2.im, f2k(O2.re, -1.f) };                                 // *-i
  cp O3w = { f2k(f2s(O3.im, O3.re), c), f2k(f2a(O3.re, O3.im), -c) };   // *W8^3
  a[0] = cpadd(E0, O0);  a[4] = cpsub(E0, O0);
  a[1] = cpadd(E1, O1w); a[5] = cpsub(E1, O1w);
  a[2] = cpadd(E2, O2w); a[6] = cpsub(E2, O2w);
  a[3] = cpadd(E3, O3w); a[7] = cpsub(E3, O3w);
}

__device__ __forceinline__ void dft8p_inv(cp* a) {
  const float c = 0.70710678118654752f;
  cp t0 = cpadd(a[0], a[4]), t1 = cpsub(a[0], a[4]);
  cp t2 = cpadd(a[2], a[6]), t3 = cpsub(a[2], a[6]);
  cp t4 = cpadd(a[1], a[5]), t5 = cpsub(a[1], a[5]);
  cp t6 = cpadd(a[3], a[7]), t7 = cpsub(a[3], a[7]);
  cp E0 = cpadd(t0, t2), E2 = cpsub(t0, t2);
  cp E1 = { f2s(t1.re, t3.im), f2a(t1.im, t3.re) };   // t1 + i*t3
  cp E3 = { f2a(t1.re, t3.im), f2s(t1.im, t3.re) };   // t1 - i*t3
  cp O0 = cpadd(t4, t6), O2 = cpsub(t4, t6);
  cp O1 = { f2s(t5.re, t7.im), f2a(t5.im, t7.re) };
  cp O3 = { f2a(t5.re, t7.im), f2s(t5.im, t7.re) };
  cp O1w = { f2k(f2s(O1.re, O1.im), c), f2k(f2a(O1.re, O1.im), c) };    // *W8^-1
  cp O2w = { f2k(O2.im, -1.f), O2.re };                                 // *+i
  cp O3w = { f2k(f2a(O3.re, O3.im), -c), f2k(f2s(O3.re, O3.im), c) };   // *W8^-3
  a[0] = cpadd(E0, O0);  a[4] = cpsub(E0, O0);
  a[1] = cpadd(E1, O1w); a[5] = cpsub(E1, O1w);
  a[2] = cpadd(E2, O2w); a[6] = cpsub(E2, O2w);
  a[3] = cpadd(E3, O3w); a[7] = cpsub(E3, O3w);
}

// One radix-8 LDS stage: 1024 butterflies, 512 threads, each thread does the
// consecutive pair (2*tid, 2*tid+1) with float2 (b64) LDS accesses.
template <bool INV>
__device__ __forceinline__ void stage8p(float* zr, float* zi, const float2* __restrict__ tw,
                                        int tid, int d, int ld, int stride) {
  const int i2 = tid * 2;
  const int j  = i2 & (d - 1);                  // even, j+1 in same block (d>=16)
  const int p  = ((i2 >> ld) << (ld + 3)) + j;
  cp v[8];
  #pragma unroll
  for (int t = 0; t < 8; ++t) {
    int q = SWZ(p + t * d);
    v[t].re = *reinterpret_cast<const float2*>(&zr[q]);
    v[t].im = *reinterpret_cast<const float2*>(&zi[q]);
  }
  if (INV) {
    #pragma unroll
    for (int k = 1; k < 8; ++k) {
      float2 wA = tw[j * k * stride], wB = tw[(j + 1) * k * stride];
      v[k] = cpmulc(v[k], make_float2(wA.x, wB.x), make_float2(wA.y, wB.y));
    }
    dft8p_inv(v);
  } else {
    dft8p_fwd(v);
    #pragma unroll
    for (int k = 1; k < 8; ++k) {
      float2 wA = tw[j * k * stride], wB = tw[(j + 1) * k * stride];
      v[k] = cpmul(v[k], make_float2(wA.x, wB.x), make_float2(wA.y, wB.y));
    }
  }
  #pragma unroll
  for (int t = 0; t < 8; ++t) {
    int q = SWZ(p + t * d);
    *reinterpret_cast<float2*>(&zr[q]) = v[t].re;
    *reinterpret_cast<float2*>(&zi[q]) = v[t].im;
  }
  __syncthreads();
}

// 16-point FFT fully in registers (finishes the 8*8*8*16 factorization).
__device__ __forceinline__ void reg16_fwd(float2* v, const float2* __restrict__ tw) {
  float2 t[8];
  #pragma unroll
  for (int k = 0; k < 8; ++k) t[k] = v[2 * k];     // j=0
  {
    const float c = 0.70710678118654752f;
    float2 t0 = cadd(t[0], t[4]), t1 = csub(t[0], t[4]);
    float2 t2 = cadd(t[2], t[6]), t3 = csub(t[2], t[6]);
    float2 t4 = cadd(t[1], t[5]), t5 = csub(t[1], t[5]);
    float2 t6 = cadd(t[3], t[7]), t7 = csub(t[3], t[7]);
    float2 E0 = cadd(t0, t2), E2 = csub(t0, t2);
    float2 E1 = make_float2(t1.x + t3.y, t1.y - t3.x);
    float2 E3 = make_float2(t1.x - t3.y, t1.y + t3.x);
    float2 O0 = cadd(t4, t6), O2 = csub(t4, t6);
    float2 O1 = make_float2(t5.x + t7.y, t5.y - t7.x);
    float2 O3 = make_float2(t5.x - t7.y, t5.y + t7.x);
    float2 O1w = make_float2(c * (O1.x + O1.y), c * (O1.y - O1.x));
    float2 O2w = make_float2(O2.y, -O2.x);
    float2 O3w = make_float2(c * (O3.y - O3.x), -c * (O3.x + O3.y));
    t[0] = cadd(E0, O0);  t[4] = csub(E0, O0);
    t[1] = cadd(E1, O1w); t[5] = csub(E1, O1w);
    t[2] = cadd(E2, O2w); t[6] = csub(E2, O2w);
    t[3] = cadd(E3, O3w); t[7] = csub(E3, O3w);
  }
  #pragma unroll
  for (int k = 0; k < 8; ++k) v[2 * k] = t[k];
  #pragma unroll
  for (int k = 0; k < 8; ++k) t[k] = v[2 * k + 1]; // j=1
  {
    const float c = 0.70710678118654752f;
    float2 t0 = cadd(t[0], t[4]), t1 = csub(t[0], t[4]);
    float2 t2 = cadd(t[2], t[6]), t3 = csub(t[2], t[6]);
    float2 t4 = cadd(t[1], t[5]), t5 = csub(t[1], t[5]);
    float2 t6 = cadd(t[3], t[7]), t7 = csub(t[3], t[7]);
    float2 E0 = cadd(t0, t2), E2 = csub(t0, t2);
    float2 E1 = make_float2(t1.x + t3.y, t1.y - t3.x);
    float2 E3 = make_float2(t1.x - t3.y, t1.y + t3.x);
    float2 O0 = cadd(t4, t6), O2 = csub(t4, t6);
    float2 O1 = make_float2(t5.x + t7.y, t5.y - t7.x);
    float2 O3 = make_float2(t5.x - t7.y, t5.y + t7.x);
    float2 O1w = make_float2(c * (O1.x + O1.y), c * (O1.y - O1.x));
    float2 O2w = make_float2(O2.y, -O2.x);
    float2 O3w = make_float2(c * (O3.y - O3.x), -c * (O3.x + O3.y));
    t[0] = cadd(E0, O0);  t[4] = csub(E0, O0);
    t[1] = cadd(E1, O1w); t[5] = csub(E1, O1w);
    t[2] = cadd(E2, O2w); t[6] = csub(E2, O2w);
    t[3] = cadd(E3, O3w); t[7] = csub(E3, O3w);
  }
  #pragma unroll
  for (int k = 1; k < 8; ++k) t[k] = cmul(t[k], tw[k * 512]);
  #pragma unroll
  for (int k = 0; k < 8; ++k) v[2 * k + 1] = t[k];
  #pragma unroll
  for (int q = 0; q < 8; ++q) {
    float2 a = v[2 * q], b = v[2 * q + 1];
    v[2 * q] = cadd(a, b); v[2 * q + 1] = csub(a, b);
  }
}

__device__ __forceinline__ void reg16_inv(float2* v, const float2* __restrict__ tw) {
  #pragma unroll
  for (int q = 0; q < 8; ++q) {
    float2 a = v[2 * q], b = v[2 * q + 1];
    v[2 * q] = cadd(a, b); v[2 * q + 1] = csub(a, b);
  }
  float2 t[8];
  #pragma unroll
  for (int k = 0; k < 8; ++k) t[k] = v[2 * k];
  {
    const float c = 0.70710678118654752f;
    float2 t0 = cadd(t[0], t[4]), t1 = csub(t[0], t[4]);
    float2 t2 = cadd(t[2], t[6]), t3 = csub(t[2], t[6]);
    float2 t4 = cadd(t[1], t[5]), t5 = csub(t[1], t[5]);
    float2 t6 = cadd(t[3], t[7]), t7 = csub(t[3], t[7]);
    float2 E0 = cadd(t0, t2), E2 = csub(t0, t2);
    float2 E1 = make_float2(t1.x - t3.y, t1.y + t3.x);
    float2 E3 = make_float2(t1.x + t3.y, t1.y - t3.x);
    float2 O0 = cadd(t4, t6), O2 = csub(t4, t6);
    float2 O1 = make_float2(t5.x - t7.y, t5.y + t7.x);
    float2 O3 = make_float2(t5.x + t7.y, t5.y - t7.x);
    float2 O1w = make_float2(c * (O1.x - O1.y), c * (O1.x + O1.y));
    float2 O2w = make_float2(-O2.y, O2.x);
    float2 O3w = make_float2(-c * (O3.x + O3.y), c * (O3.x - O3.y));
    t[0] = cadd(E0, O0);  t[4] = csub(E0, O0);
    t[1] = cadd(E1, O1w); t[5] = csub(E1, O1w);
    t[2] = cadd(E2, O2w); t[6] = csub(E2, O2w);
    t[3] = cadd(E3, O3w); t[7] = csub(E3, O3w);
  }
  #pragma unroll
  for (int k = 0; k < 8; ++k) v[2 * k] = t[k];
  #pragma unroll
  for (int k = 0; k < 8; ++k) t[k] = cmulc(v[2 * k + 1], tw[k * 512]);
  {
    const float c = 0.70710678118654752f;
    float2 t0 = cadd(t[0], t[4]), t1 = csub(t[0], t[4]);
    float2 t2 = cadd(t[2], t[6]), t3 = csub(t[2], t[6]);
    float2 t4 = cadd(t[1], t[5]), t5 = csub(t[1], t[5]);
    float2 t6 = cadd(t[3], t[7]), t7 = csub(t[3], t[7]);
    float2 E0 = cadd(t0, t2), E2 = csub(t0, t2);
    float2 E1 = make_float2(t1.x - t3.y, t1.y + t3.x);
    float2 E3 = make_float2(t1.x + t3.y, t1.y - t3.x);
    float2 O0 = cadd(t4, t6), O2 = csub(t4, t6);
    float2 O1 = make_float2(t5.x - t7.y, t5.y + t7.x);
    float2 O3 = make_float2(t5.x + t7.y, t5.y - t7.x);
    float2 O1w = make_float2(c * (O1.x - O1.y), c * (O1.x + O1.y));
    float2 O2w = make_float2(-O2.y, O2.x);
    float2 O3w = make_float2(-c * (O3.x + O3.y), c * (O3.x - O3.y));
    t[0] = cadd(E0, O0);  t[4] = csub(E0, O0);
    t[1] = cadd(E1, O1w); t[5] = csub(E1, O1w);
    t[2] = cadd(E2, O2w); t[6] = csub(E2, O2w);
    t[3] = cadd(E3, O3w); t[7] = csub(E3, O3w);
  }
  #pragma unroll
  for (int k = 0; k < 8; ++k) v[2 * k + 1] = t[k];
}

// ---------------------------------------------------------------------------
// Masked MFN kernel generation. grid (K/256, 24); block y covers 16 channels.
// ---------------------------------------------------------------------------
__global__ __launch_bounds__(256) void gen_mk(
    const float* __restrict__ mask_mean, const float* __restrict__ mask_sigma,
    const float* __restrict__ gfw, const float* __restrict__ gfb,
    const float* __restrict__ gg,  const float* __restrict__ gmu,
    const float* __restrict__ lin_w, const float* __restrict__ lin_b,
    const float* __restrict__ out_w, const float* __restrict__ out_b,
    float* __restrict__ mk) {
  const int t = threadIdx.x;
  const int k = blockIdx.x * 256 + t;
  const int c0 = blockIdx.y * 16;
  const float xp = -1.0f + 2.0f * (float)k / (float)(K_ - 1);

  float h[KH_];
  #pragma unroll
  for (int j = 0; j < KH_; ++j) {
    float d   = gg[j] * (xp - gmu[j]);
    float env = expf(-0.5f * d * d);
    float su  = sinf(OMEGA_ * (xp * gfw[j]) + gfb[j]);
    h[j] = env * su;
  }
  for (int i = 0; i < NL_; ++i) {
    const float* lw = lin_w + i * KH_ * KH_;
    const int go = (i + 1) * KH_;
    float nh[KH_];
    #pragma unroll
    for (int h2 = 0; h2 < KH_; ++h2) {
      float acc = lin_b[i * KH_ + h2];
      #pragma unroll
      for (int j = 0; j < KH_; ++j) acc = fmaf(h[j], lw[h2 * KH_ + j], acc);
      float d   = gg[go + h2] * (xp - gmu[go + h2]);
      float env = expf(-0.5f * d * d);
      float su  = sinf(OMEGA_ * (xp * gfw[go + h2]) + gfb[go + h2]);
      nh[h2] = acc * (env * su);
    }
    #pragma unroll
    for (int j = 0; j < KH_; ++j) h[j] = nh[j];
  }
  float mw = (xp - mask_mean[0]) / mask_sigma[0];
  float ms = expf(-0.5f * mw * mw) * rsqrtf((float)(C_ * K_));
  #pragma unroll
  for (int j = 0; j < KH_; ++j) h[j] *= ms;

  for (int cc = 0; cc < 16; ++cc) {
    int c = c0 + cc;
    float acc = out_b[c] * ms;
    #pragma unroll
    for (int j = 0; j < KH_; ++j) acc = fmaf(h[j], out_w[c * KH_ + j], acc);
    mk[(size_t)c * K_ + k] = acc;
  }
}

// ---------------------------------------------------------------------------
// Kernel spectrum (scrambled mixed-radix order), scaled by 1/NFFT. 512 thr.
// ---------------------------------------------------------------------------
__global__ __launch_bounds__(512, 4) void fft_h(const float* __restrict__ mk,
                                                const float2* __restrict__ tw,
                                                float2* __restrict__ Hspec) {
  extern __shared__ float smem[];
  float* zr = smem;
  float* zi = smem + NFFT;
  const int c = blockIdx.x;
  const int tid = threadIdx.x;
  const float4* row4 = reinterpret_cast<const float4*>(mk + (size_t)c * K_);
  const float4 z4 = make_float4(0.f, 0.f, 0.f, 0.f);
  for (int i = tid; i < K_ / 4; i += 512) {
    int p = i * 4;
    *reinterpret_cast<float4*>(&zr[SWZ(p)]) = row4[i];
    *reinterpret_cast<float4*>(&zi[SWZ(p)]) = z4;
    *reinterpret_cast<float4*>(&zr[SWZ(p + K_)]) = z4;
    *reinterpret_cast<float4*>(&zi[SWZ(p + K_)]) = z4;
  }
  __syncthreads();
  stage8p<false>(zr, zi, tw, tid, 1024, 10, 1);
  stage8p<false>(zr, zi, tw, tid, 128, 7, 8);
  stage8p<false>(zr, zi, tw, tid, 16, 4, 64);

  const float inv = 1.0f / (float)NFFT;
  float2* outp = Hspec + (size_t)c * NFFT;
  {
    const int base = tid * 16;
    const int pb = SWZ(base);
    const int rot = tid & 3;
    float2 v[16];
    #pragma unroll
    for (int iq = 0; iq < 4; ++iq) {
      int q4 = (iq + rot) & 3;
      float4 re = *reinterpret_cast<const float4*>(&zr[pb + q4 * 4]);
      float4 im = *reinterpret_cast<const float4*>(&zi[pb + q4 * 4]);
      v[q4 * 4 + 0] = make_float2(re.x, im.x);
      v[q4 * 4 + 1] = make_float2(re.y, im.y);
      v[q4 * 4 + 2] = make_float2(re.z, im.z);
      v[q4 * 4 + 3] = make_float2(re.w, im.w);
    }
    reg16_fwd(v, tw);
    #pragma unroll
    for (int q = 0; q < 16; ++q) outp[base + q] = make_float2(v[q].x * inv, v[q].y * inv);
  }
}

// ---------------------------------------------------------------------------
// FFT convolution, two batches per block packed as real/imag. 512 threads.
// ---------------------------------------------------------------------------
__global__ __launch_bounds__(512, 4) void fft_conv(const float* __restrict__ x,
                                                   const float2* __restrict__ Hspec,
                                                   const float2* __restrict__ tw,
                                                   float* __restrict__ y) {
  extern __shared__ float smem[];
  float* zr = smem;
  float* zi = smem + NFFT;
  const int c  = blockIdx.x % C_;
  const int pr = blockIdx.x / C_;
  const int b1 = 2 * pr, b2 = b1 + 1;
  const int tid = threadIdx.x;
  const float4* x1 = reinterpret_cast<const float4*>(x + ((size_t)b1 * C_ + c) * L_);
  const float4* x2 = reinterpret_cast<const float4*>(x + ((size_t)b2 * C_ + c) * L_);
  const float4 z4 = make_float4(0.f, 0.f, 0.f, 0.f);
  for (int i = tid; i < L_ / 4; i += 512) {
    int p = i * 4;
    *reinterpret_cast<float4*>(&zr[SWZ(p)]) = x1[i];
    *reinterpret_cast<float4*>(&zi[SWZ(p)]) = x2[i];
    *reinterpret_cast<float4*>(&zr[SWZ(p + L_)]) = z4;
    *reinterpret_cast<float4*>(&zi[SWZ(p + L_)]) = z4;
  }
  __syncthreads();
  stage8p<false>(zr, zi, tw, tid, 1024, 10, 1);
  stage8p<false>(zr, zi, tw, tid, 128, 7, 8);
  stage8p<false>(zr, zi, tw, tid, 16, 4, 64);

  const float2* Hc = Hspec + (size_t)c * NFFT;
  {
    const int base = tid * 16;
    const int pb = SWZ(base);
    const int rot = tid & 3;
    float2 v[16];
    #pragma unroll
    for (int iq = 0; iq < 4; ++iq) {
      int q4 = (iq + rot) & 3;
      float4 re = *reinterpret_cast<const float4*>(&zr[pb + q4 * 4]);
      float4 im = *reinterpret_cast<const float4*>(&zi[pb + q4 * 4]);
      v[q4 * 4 + 0] = make_float2(re.x, im.x);
      v[q4 * 4 + 1] = make_float2(re.y, im.y);
      v[q4 * 4 + 2] = make_float2(re.z, im.z);
      v[q4 * 4 + 3] = make_float2(re.w, im.w);
    }
    reg16_fwd(v, tw);
    #pragma unroll
    for (int q = 0; q < 16; ++q) v[q] = cmul(v[q], Hc[base + q]);
    reg16_inv(v, tw);
    #pragma unroll
    for (int iq = 0; iq < 4; ++iq) {
      int q4 = (iq + rot) & 3;
      float4 re = make_float4(v[q4 * 4 + 0].x, v[q4 * 4 + 1].x, v[q4 * 4 + 2].x, v[q4 * 4 + 3].x);
      float4 im = make_float4(v[q4 * 4 + 0].y, v[q4 * 4 + 1].y, v[q4 * 4 + 2].y, v[q4 * 4 + 3].y);
      *reinterpret_cast<float4*>(&zr[pb + q4 * 4]) = re;
      *reinterpret_cast<float4*>(&zi[pb + q4 * 4]) = im;
    }
  }
  __syncthreads();
  stage8p<true>(zr, zi, tw, tid, 16, 4, 64);
  stage8p<true>(zr, zi, tw, tid, 128, 7, 8);
  stage8p<true>(zr, zi, tw, tid, 1024, 10, 1);

  float4* y1 = reinterpret_cast<float4*>(y + ((size_t)b1 * C_ + c) * L_);
  float4* y2 = reinterpret_cast<float4*>(y + ((size_t)b2 * C_ + c) * L_);
  for (int i = tid; i < L_ / 4; i += 512) {
    int p = i * 4;
    y1[i] = *reinterpret_cast<const float4*>(&zr[SWZ(p)]);
    y2[i] = *reinterpret_cast<const float4*>(&zi[SWZ(p)]);
  }
}

// ---------------------------------------------------------------------------
// Pointwise 1x1 conv: out[b][o][l] = sum_c pw[o][c] * y[b][c][l]
// fp32 GEMM: 128x128 tile, BK=16, 256 threads, 2x2 blocks of 4x4 per thread,
// register-prefetch software pipeline. grid = (L/128, HID/128, B)
// ---------------------------------------------------------------------------
#define MT 128
#define NT 128
#define KT 16
#define LDT 132
__global__ __launch_bounds__(256, 4) void pw_gemm(const float* __restrict__ y,
                                                  const float* __restrict__ pw,
                                                  float* __restrict__ out) {
  const int b  = blockIdx.z;
  const int m0 = blockIdx.y * MT;
  const int n0 = blockIdx.x * NT;
  __shared__ float As[KT][LDT];   // [k][m]
  __shared__ float Bs[KT][LDT];   // [k][n]
  const int tid = threadIdx.x;
  const int tx = tid & 15, ty = tid >> 4;
  const int arow = tid >> 2, ac4 = (tid & 3) << 2;   // + rep*64 rows
  const int brow = tid >> 5, bcc = (tid & 31) << 2;  // + rep*8 rows
  float acc[2][2][4][4] = {{{{0.f}}}};
  const float* yb = y + (size_t)b * C_ * L_;

  float4 pa[2], pbv[2];
  #pragma unroll
  for (int rep = 0; rep < 2; ++rep) {
    pa[rep]  = *reinterpret_cast<const float4*>(pw + (size_t)(m0 + arow + rep * 64) * C_ + ac4);
    pbv[rep] = *reinterpret_cast<const float4*>(yb + (size_t)(brow + rep * 8) * L_ + n0 + bcc);
  }
  for (int k0 = 0; k0 < C_; k0 += KT) {
    #pragma unroll
    for (int rep = 0; rep < 2; ++rep) {
      int row = arow + rep * 64;
      As[ac4 + 0][row] = pa[rep].x; As[ac4 + 1][row] = pa[rep].y;
      As[ac4 + 2][row] = pa[rep].z; As[ac4 + 3][row] = pa[rep].w;
      *reinterpret_cast<float4*>(&Bs[brow + rep * 8][bcc]) = pbv[rep];
    }
    __syncthreads();
    if (k0 + KT < C_) {
      #pragma unroll
      for (int rep = 0; rep < 2; ++rep) {
        pa[rep]  = *reinterpret_cast<const float4*>(pw + (size_t)(m0 + arow + rep * 64) * C_ + (k0 + KT) + ac4);
        pbv[rep] = *reinterpret_cast<const float4*>(yb + (size_t)(k0 + KT + brow + rep * 8) * L_ + n0 + bcc);
      }
    }
    #pragma unroll
    for (int kk = 0; kk < KT; ++kk) {
      float4 a0 = *reinterpret_cast<const float4*>(&As[kk][ty * 4]);
      float4 a1 = *reinterpret_cast<const float4*>(&As[kk][ty * 4 + 64]);
      float4 b0 = *reinterpret_cast<const float4*>(&Bs[kk][tx * 4]);
      float4 b1 = *reinterpret_cast<const float4*>(&Bs[kk][tx * 4 + 64]);
      float av[2][4] = {{a0.x, a0.y, a0.z, a0.w}, {a1.x, a1.y, a1.z, a1.w}};
      float bv[2][4] = {{b0.x, b0.y, b0.z, b0.w}, {b1.x, b1.y, b1.z, b1.w}};
      #pragma unroll
      for (int ri = 0; ri < 2; ++ri)
        #pragma unroll
        for (int rj = 0; rj < 2; ++rj)
          #pragma unroll
          for (int i = 0; i < 4; ++i)
            #pragma unroll
            for (int j = 0; j < 4; ++j)
              acc[ri][rj][i][j] = fmaf(av[ri][i], bv[rj][j], acc[ri][rj][i][j]);
    }
    __syncthreads();
  }
  #pragma unroll
  for (int ri = 0; ri < 2; ++ri)
    #pragma unroll
    for (int i = 0; i < 4; ++i) {
      int grow = m0 + ty * 4 + i + ri * 64;
      float* orow = out + ((size_t)b * HID_ + grow) * L_ + n0;
      #pragma unroll
      for (int rj = 0; rj < 2; ++rj) {
        float4 v = make_float4(acc[ri][rj][i][0], acc[ri][rj][i][1],
                               acc[ri][rj][i][2], acc[ri][rj][i][3]);
        *reinterpret_cast<float4*>(orow + tx * 4 + rj * 64) = v;
      }
    }
}

// ---------------------------------------------------------------------------
extern "C" void kernel_launch(void* const* d_in, const int* in_sizes, int n_in,
                              void* d_out, int out_size, void* d_ws, size_t ws_size,
                              hipStream_t stream) {
  (void)in_sizes; (void)n_in; (void)out_size; (void)ws_size;
  const float* x          = (const float*)d_in[0];
  const float* mask_mean  = (const float*)d_in[1];
  const float* mask_sigma = (const float*)d_in[2];
  const float* gfw        = (const float*)d_in[3];
  const float* gfb        = (const float*)d_in[4];
  const float* gg         = (const float*)d_in[5];
  const float* gmu        = (const float*)d_in[6];
  const float* lin_w      = (const float*)d_in[7];
  const float* lin_b      = (const float*)d_in[8];
  const float* out_w      = (const float*)d_in[9];
  const float* out_b      = (const float*)d_in[10];
  const float* pw_w       = (const float*)d_in[11];
  float* out = (float*)d_out;

  // workspace layout (16B-aligned):
  //   tw    : float2[NFFT]          65536 B
  //   mk    : float [C*K]         6291456 B
  //   Hspec : float2[C*NFFT]     25165824 B
  //   y     : float [B*C*L]     100663296 B   (total ~132.3 MB)
  char* ws = (char*)d_ws;
  float2* tw = (float2*)ws;
  float*  mk = (float*)(ws + 65536);
  float2* Hs = (float2*)(ws + 65536 + 6291456);
  float*  y  = (float*)(ws + 65536 + 6291456 + 25165824);

  gen_tw<<<NFFT / 256, 256, 0, stream>>>(tw);
  gen_mk<<<dim3(K_ / 256, 24), 256, 0, stream>>>(mask_mean, mask_sigma, gfw, gfb, gg, gmu,
                                                 lin_w, lin_b, out_w, out_b, mk);
  fft_h<<<C_, 512, 2 * NFFT * sizeof(float), stream>>>(mk, tw, Hs);
  fft_conv<<<(B_ / 2) * C_, 512, 2 * NFFT * sizeof(float), stream>>>(x, Hs, tw, y);
  pw_gemm<<<dim3(L_ / NT, HID_ / MT, B_), 256, 0, stream>>>(y, pw_w, out);
}

// Round 5
// 1015.981 us; speedup vs baseline: 1.6678x; 1.6678x over previous
//
#include <hip/hip_runtime.h>
#include <math.h>

#define B_    16
#define C_    384
#define L_    4096
#define K_    4096
#define KH_   32
#define NL_   3
#define HID_  384
#define NFFT  8192
#define OMEGA_ 976.0f

// LDS swizzle: XOR bit4 of the float index with bit7 -> stage strides stay
// near-conflict-free and 16-aligned chunks remain contiguous. Even addresses
// keep pair-contiguity (bit0 untouched), so float2/float4 accesses are safe.
#define SWZ(a) ((a) ^ ((((a) >> 7) & 1) << 4))

// ---------------------------------------------------------------------------
// Twiddles: tw[t] = exp(-2*pi*i*t/NFFT), t = 0..NFFT-1
// ---------------------------------------------------------------------------
__global__ __launch_bounds__(256) void gen_tw(float2* __restrict__ tw) {
  int j = blockIdx.x * 256 + threadIdx.x;
  if (j < NFFT) {
    double a = -2.0 * 3.14159265358979323846 * (double)j / (double)NFFT;
    double s, c;
    sincos(a, &s, &c);
    tw[j] = make_float2((float)c, (float)s);
  }
}

// ------------------------- scalar complex helpers --------------------------
__device__ __forceinline__ float2 cadd(float2 a, float2 b) { return make_float2(a.x + b.x, a.y + b.y); }
__device__ __forceinline__ float2 csub(float2 a, float2 b) { return make_float2(a.x - b.x, a.y - b.y); }
__device__ __forceinline__ float2 cmul(float2 a, float2 b) { return make_float2(a.x * b.x - a.y * b.y, a.x * b.y + a.y * b.x); }
__device__ __forceinline__ float2 cmulc(float2 a, float2 b) { // a * conj(b)
  return make_float2(a.x * b.x + a.y * b.y, a.y * b.x - a.x * b.y);
}

// ------------------------- packed-pair complex (2 butterflies) -------------
struct cp { float2 re, im; };
__device__ __forceinline__ float2 f2a(float2 a, float2 b) { return make_float2(a.x + b.x, a.y + b.y); }
__device__ __forceinline__ float2 f2s(float2 a, float2 b) { return make_float2(a.x - b.x, a.y - b.y); }
__device__ __forceinline__ float2 f2m(float2 a, float2 b) { return make_float2(a.x * b.x, a.y * b.y); }
__device__ __forceinline__ float2 f2k(float2 a, float s)  { return make_float2(a.x * s, a.y * s); }
__device__ __forceinline__ cp cpadd(cp a, cp b) { return {f2a(a.re, b.re), f2a(a.im, b.im)}; }
__device__ __forceinline__ cp cpsub(cp a, cp b) { return {f2s(a.re, b.re), f2s(a.im, b.im)}; }
// a * (wr + i*wi), per-element twiddles
__device__ __forceinline__ cp cpmul(cp a, float2 wr, float2 wi) {
  return { f2s(f2m(a.re, wr), f2m(a.im, wi)), f2a(f2m(a.re, wi), f2m(a.im, wr)) };
}
__device__ __forceinline__ cp cpmulc(cp a, float2 wr, float2 wi) { // a * conj(w)
  return { f2a(f2m(a.re, wr), f2m(a.im, wi)), f2s(f2m(a.im, wr), f2m(a.re, wi)) };
}

// 8-point DFT on packed pairs (forward, W8 = exp(-i*pi/4)), in place
__device__ __forceinline__ void dft8p_fwd(cp* a) {
  const float c = 0.70710678118654752f;
  cp t0 = cpadd(a[0], a[4]), t1 = cpsub(a[0], a[4]);
  cp t2 = cpadd(a[2], a[6]), t3 = cpsub(a[2], a[6]);
  cp t4 = cpadd(a[1], a[5]), t5 = cpsub(a[1], a[5]);
  cp t6 = cpadd(a[3], a[7]), t7 = cpsub(a[3], a[7]);
  cp E0 = cpadd(t0, t2), E2 = cpsub(t0, t2);
  cp E1 = { f2a(t1.re, t3.im), f2s(t1.im, t3.re) };   // t1 - i*t3
  cp E3 = { f2s(t1.re, t3.im), f2a(t1.im, t3.re) };   // t1 + i*t3
  cp O0 = cpadd(t4, t6), O2 = cpsub(t4, t6);
  cp O1 = { f2a(t5.re, t7.im), f2s(t5.im, t7.re) };
  cp O3 = { f2s(t5.re, t7.im), f2a(t5.im, t7.re) };
  cp O1w = { f2k(f2a(O1.re, O1.im), c), f2k(f2s(O1.im, O1.re), c) };    // *W8^1
  cp O2w = { O2.im, f2k(O2.re, -1.f) };                                 // *-i
  cp O3w = { f2k(f2s(O3.im, O3.re), c), f2k(f2a(O3.re, O3.im), -c) };   // *W8^3
  a[0] = cpadd(E0, O0);  a[4] = cpsub(E0, O0);
  a[1] = cpadd(E1, O1w); a[5] = cpsub(E1, O1w);
  a[2] = cpadd(E2, O2w); a[6] = cpsub(E2, O2w);
  a[3] = cpadd(E3, O3w); a[7] = cpsub(E3, O3w);
}

__device__ __forceinline__ void dft8p_inv(cp* a) {
  const float c = 0.70710678118654752f;
  cp t0 = cpadd(a[0], a[4]), t1 = cpsub(a[0], a[4]);
  cp t2 = cpadd(a[2], a[6]), t3 = cpsub(a[2], a[6]);
  cp t4 = cpadd(a[1], a[5]), t5 = cpsub(a[1], a[5]);
  cp t6 = cpadd(a[3], a[7]), t7 = cpsub(a[3], a[7]);
  cp E0 = cpadd(t0, t2), E2 = cpsub(t0, t2);
  cp E1 = { f2s(t1.re, t3.im), f2a(t1.im, t3.re) };   // t1 + i*t3
  cp E3 = { f2a(t1.re, t3.im), f2s(t1.im, t3.re) };   // t1 - i*t3
  cp O0 = cpadd(t4, t6), O2 = cpsub(t4, t6);
  cp O1 = { f2s(t5.re, t7.im), f2a(t5.im, t7.re) };
  cp O3 = { f2a(t5.re, t7.im), f2s(t5.im, t7.re) };
  cp O1w = { f2k(f2s(O1.re, O1.im), c), f2k(f2a(O1.re, O1.im), c) };    // *W8^-1
  cp O2w = { f2k(O2.im, -1.f), O2.re };                                 // *+i
  cp O3w = { f2k(f2a(O3.re, O3.im), -c), f2k(f2s(O3.re, O3.im), c) };   // *W8^-3
  a[0] = cpadd(E0, O0);  a[4] = cpsub(E0, O0);
  a[1] = cpadd(E1, O1w); a[5] = cpsub(E1, O1w);
  a[2] = cpadd(E2, O2w); a[6] = cpsub(E2, O2w);
  a[3] = cpadd(E3, O3w); a[7] = cpsub(E3, O3w);
}

// One radix-8 LDS stage: 1024 butterflies, 512 threads, each thread does the
// consecutive pair (2*tid, 2*tid+1) with float2 (b64) LDS accesses.
template <bool INV>
__device__ __forceinline__ void stage8p(float* zr, float* zi, const float2* __restrict__ tw,
                                        int tid, int d, int ld, int stride) {
  const int i2 = tid * 2;
  const int j  = i2 & (d - 1);                  // even, j+1 in same block (d>=16)
  const int p  = ((i2 >> ld) << (ld + 3)) + j;
  cp v[8];
  #pragma unroll
  for (int t = 0; t < 8; ++t) {
    int q = SWZ(p + t * d);
    v[t].re = *reinterpret_cast<const float2*>(&zr[q]);
    v[t].im = *reinterpret_cast<const float2*>(&zi[q]);
  }
  if (INV) {
    #pragma unroll
    for (int k = 1; k < 8; ++k) {
      float2 wA = tw[j * k * stride], wB = tw[(j + 1) * k * stride];
      v[k] = cpmulc(v[k], make_float2(wA.x, wB.x), make_float2(wA.y, wB.y));
    }
    dft8p_inv(v);
  } else {
    dft8p_fwd(v);
    #pragma unroll
    for (int k = 1; k < 8; ++k) {
      float2 wA = tw[j * k * stride], wB = tw[(j + 1) * k * stride];
      v[k] = cpmul(v[k], make_float2(wA.x, wB.x), make_float2(wA.y, wB.y));
    }
  }
  #pragma unroll
  for (int t = 0; t < 8; ++t) {
    int q = SWZ(p + t * d);
    *reinterpret_cast<float2*>(&zr[q]) = v[t].re;
    *reinterpret_cast<float2*>(&zi[q]) = v[t].im;
  }
  __syncthreads();
}

// 16-point FFT fully in registers (finishes the 8*8*8*16 factorization).
__device__ __forceinline__ void reg16_fwd(float2* v, const float2* __restrict__ tw) {
  float2 t[8];
  #pragma unroll
  for (int k = 0; k < 8; ++k) t[k] = v[2 * k];     // j=0
  {
    const float c = 0.70710678118654752f;
    float2 t0 = cadd(t[0], t[4]), t1 = csub(t[0], t[4]);
    float2 t2 = cadd(t[2], t[6]), t3 = csub(t[2], t[6]);
    float2 t4 = cadd(t[1], t[5]), t5 = csub(t[1], t[5]);
    float2 t6 = cadd(t[3], t[7]), t7 = csub(t[3], t[7]);
    float2 E0 = cadd(t0, t2), E2 = csub(t0, t2);
    float2 E1 = make_float2(t1.x + t3.y, t1.y - t3.x);
    float2 E3 = make_float2(t1.x - t3.y, t1.y + t3.x);
    float2 O0 = cadd(t4, t6), O2 = csub(t4, t6);
    float2 O1 = make_float2(t5.x + t7.y, t5.y - t7.x);
    float2 O3 = make_float2(t5.x - t7.y, t5.y + t7.x);
    float2 O1w = make_float2(c * (O1.x + O1.y), c * (O1.y - O1.x));
    float2 O2w = make_float2(O2.y, -O2.x);
    float2 O3w = make_float2(c * (O3.y - O3.x), -c * (O3.x + O3.y));
    t[0] = cadd(E0, O0);  t[4] = csub(E0, O0);
    t[1] = cadd(E1, O1w); t[5] = csub(E1, O1w);
    t[2] = cadd(E2, O2w); t[6] = csub(E2, O2w);
    t[3] = cadd(E3, O3w); t[7] = csub(E3, O3w);
  }
  #pragma unroll
  for (int k = 0; k < 8; ++k) v[2 * k] = t[k];
  #pragma unroll
  for (int k = 0; k < 8; ++k) t[k] = v[2 * k + 1]; // j=1
  {
    const float c = 0.70710678118654752f;
    float2 t0 = cadd(t[0], t[4]), t1 = csub(t[0], t[4]);
    float2 t2 = cadd(t[2], t[6]), t3 = csub(t[2], t[6]);
    float2 t4 = cadd(t[1], t[5]), t5 = csub(t[1], t[5]);
    float2 t6 = cadd(t[3], t[7]), t7 = csub(t[3], t[7]);
    float2 E0 = cadd(t0, t2), E2 = csub(t0, t2);
    float2 E1 = make_float2(t1.x + t3.y, t1.y - t3.x);
    float2 E3 = make_float2(t1.x - t3.y, t1.y + t3.x);
    float2 O0 = cadd(t4, t6), O2 = csub(t4, t6);
    float2 O1 = make_float2(t5.x + t7.y, t5.y - t7.x);
    float2 O3 = make_float2(t5.x - t7.y, t5.y + t7.x);
    float2 O1w = make_float2(c * (O1.x + O1.y), c * (O1.y - O1.x));
    float2 O2w = make_float2(O2.y, -O2.x);
    float2 O3w = make_float2(c * (O3.y - O3.x), -c * (O3.x + O3.y));
    t[0] = cadd(E0, O0);  t[4] = csub(E0, O0);
    t[1] = cadd(E1, O1w); t[5] = csub(E1, O1w);
    t[2] = cadd(E2, O2w); t[6] = csub(E2, O2w);
    t[3] = cadd(E3, O3w); t[7] = csub(E3, O3w);
  }
  #pragma unroll
  for (int k = 1; k < 8; ++k) t[k] = cmul(t[k], tw[k * 512]);
  #pragma unroll
  for (int k = 0; k < 8; ++k) v[2 * k + 1] = t[k];
  #pragma unroll
  for (int q = 0; q < 8; ++q) {
    float2 a = v[2 * q], b = v[2 * q + 1];
    v[2 * q] = cadd(a, b); v[2 * q + 1] = csub(a, b);
  }
}

__device__ __forceinline__ void reg16_inv(float2* v, const float2* __restrict__ tw) {
  #pragma unroll
  for (int q = 0; q < 8; ++q) {
    float2 a = v[2 * q], b = v[2 * q + 1];
    v[2 * q] = cadd(a, b); v[2 * q + 1] = csub(a, b);
  }
  float2 t[8];
  #pragma unroll
  for (int k = 0; k < 8; ++k) t[k] = v[2 * k];
  {
    const float c = 0.70710678118654752f;
    float2 t0 = cadd(t[0], t[4]), t1 = csub(t[0], t[4]);
    float2 t2 = cadd(t[2], t[6]), t3 = csub(t[2], t[6]);
    float2 t4 = cadd(t[1], t[5]), t5 = csub(t[1], t[5]);
    float2 t6 = cadd(t[3], t[7]), t7 = csub(t[3], t[7]);
    float2 E0 = cadd(t0, t2), E2 = csub(t0, t2);
    float2 E1 = make_float2(t1.x - t3.y, t1.y + t3.x);
    float2 E3 = make_float2(t1.x + t3.y, t1.y - t3.x);
    float2 O0 = cadd(t4, t6), O2 = csub(t4, t6);
    float2 O1 = make_float2(t5.x - t7.y, t5.y + t7.x);
    float2 O3 = make_float2(t5.x + t7.y, t5.y - t7.x);
    float2 O1w = make_float2(c * (O1.x - O1.y), c * (O1.x + O1.y));
    float2 O2w = make_float2(-O2.y, O2.x);
    float2 O3w = make_float2(-c * (O3.x + O3.y), c * (O3.x - O3.y));
    t[0] = cadd(E0, O0);  t[4] = csub(E0, O0);
    t[1] = cadd(E1, O1w); t[5] = csub(E1, O1w);
    t[2] = cadd(E2, O2w); t[6] = csub(E2, O2w);
    t[3] = cadd(E3, O3w); t[7] = csub(E3, O3w);
  }
  #pragma unroll
  for (int k = 0; k < 8; ++k) v[2 * k] = t[k];
  #pragma unroll
  for (int k = 0; k < 8; ++k) t[k] = cmulc(v[2 * k + 1], tw[k * 512]);
  {
    const float c = 0.70710678118654752f;
    float2 t0 = cadd(t[0], t[4]), t1 = csub(t[0], t[4]);
    float2 t2 = cadd(t[2], t[6]), t3 = csub(t[2], t[6]);
    float2 t4 = cadd(t[1], t[5]), t5 = csub(t[1], t[5]);
    float2 t6 = cadd(t[3], t[7]), t7 = csub(t[3], t[7]);
    float2 E0 = cadd(t0, t2), E2 = csub(t0, t2);
    float2 E1 = make_float2(t1.x - t3.y, t1.y + t3.x);
    float2 E3 = make_float2(t1.x + t3.y, t1.y - t3.x);
    float2 O0 = cadd(t4, t6), O2 = csub(t4, t6);
    float2 O1 = make_float2(t5.x - t7.y, t5.y + t7.x);
    float2 O3 = make_float2(t5.x + t7.y, t5.y - t7.x);
    float2 O1w = make_float2(c * (O1.x - O1.y), c * (O1.x + O1.y));
    float2 O2w = make_float2(-O2.y, O2.x);
    float2 O3w = make_float2(-c * (O3.x + O3.y), c * (O3.x - O3.y));
    t[0] = cadd(E0, O0);  t[4] = csub(E0, O0);
    t[1] = cadd(E1, O1w); t[5] = csub(E1, O1w);
    t[2] = cadd(E2, O2w); t[6] = csub(E2, O2w);
    t[3] = cadd(E3, O3w); t[7] = csub(E3, O3w);
  }
  #pragma unroll
  for (int k = 0; k < 8; ++k) v[2 * k + 1] = t[k];
}

// ---------------------------------------------------------------------------
// Masked MFN kernel generation. grid (K/256, 24); block y covers 16 channels.
// ---------------------------------------------------------------------------
__global__ __launch_bounds__(256) void gen_mk(
    const float* __restrict__ mask_mean, const float* __restrict__ mask_sigma,
    const float* __restrict__ gfw, const float* __restrict__ gfb,
    const float* __restrict__ gg,  const float* __restrict__ gmu,
    const float* __restrict__ lin_w, const float* __restrict__ lin_b,
    const float* __restrict__ out_w, const float* __restrict__ out_b,
    float* __restrict__ mk) {
  const int t = threadIdx.x;
  const int k = blockIdx.x * 256 + t;
  const int c0 = blockIdx.y * 16;
  const float xp = -1.0f + 2.0f * (float)k / (float)(K_ - 1);

  float h[KH_];
  #pragma unroll
  for (int j = 0; j < KH_; ++j) {
    float d   = gg[j] * (xp - gmu[j]);
    float env = expf(-0.5f * d * d);
    float su  = sinf(OMEGA_ * (xp * gfw[j]) + gfb[j]);
    h[j] = env * su;
  }
  for (int i = 0; i < NL_; ++i) {
    const float* lw = lin_w + i * KH_ * KH_;
    const int go = (i + 1) * KH_;
    float nh[KH_];
    #pragma unroll
    for (int h2 = 0; h2 < KH_; ++h2) {
      float acc = lin_b[i * KH_ + h2];
      #pragma unroll
      for (int j = 0; j < KH_; ++j) acc = fmaf(h[j], lw[h2 * KH_ + j], acc);
      float d   = gg[go + h2] * (xp - gmu[go + h2]);
      float env = expf(-0.5f * d * d);
      float su  = sinf(OMEGA_ * (xp * gfw[go + h2]) + gfb[go + h2]);
      nh[h2] = acc * (env * su);
    }
    #pragma unroll
    for (int j = 0; j < KH_; ++j) h[j] = nh[j];
  }
  float mw = (xp - mask_mean[0]) / mask_sigma[0];
  float ms = expf(-0.5f * mw * mw) * rsqrtf((float)(C_ * K_));
  #pragma unroll
  for (int j = 0; j < KH_; ++j) h[j] *= ms;

  for (int cc = 0; cc < 16; ++cc) {
    int c = c0 + cc;
    float acc = out_b[c] * ms;
    #pragma unroll
    for (int j = 0; j < KH_; ++j) acc = fmaf(h[j], out_w[c * KH_ + j], acc);
    mk[(size_t)c * K_ + k] = acc;
  }
}

// ---------------------------------------------------------------------------
// Kernel spectrum (scrambled mixed-radix order), scaled by 1/NFFT. 512 thr.
// ---------------------------------------------------------------------------
__global__ __launch_bounds__(512, 4) void fft_h(const float* __restrict__ mk,
                                                const float2* __restrict__ tw,
                                                float2* __restrict__ Hspec) {
  extern __shared__ float smem[];
  float* zr = smem;
  float* zi = smem + NFFT;
  const int c = blockIdx.x;
  const int tid = threadIdx.x;
  const float4* row4 = reinterpret_cast<const float4*>(mk + (size_t)c * K_);
  const float4 z4 = make_float4(0.f, 0.f, 0.f, 0.f);
  for (int i = tid; i < K_ / 4; i += 512) {
    int p = i * 4;
    *reinterpret_cast<float4*>(&zr[SWZ(p)]) = row4[i];
    *reinterpret_cast<float4*>(&zi[SWZ(p)]) = z4;
    *reinterpret_cast<float4*>(&zr[SWZ(p + K_)]) = z4;
    *reinterpret_cast<float4*>(&zi[SWZ(p + K_)]) = z4;
  }
  __syncthreads();
  stage8p<false>(zr, zi, tw, tid, 1024, 10, 1);
  stage8p<false>(zr, zi, tw, tid, 128, 7, 8);
  stage8p<false>(zr, zi, tw, tid, 16, 4, 64);

  const float inv = 1.0f / (float)NFFT;
  float2* outp = Hspec + (size_t)c * NFFT;
  {
    const int base = tid * 16;
    const int pb = SWZ(base);
    const int rot = tid & 3;
    float2 v[16];
    #pragma unroll
    for (int iq = 0; iq < 4; ++iq) {
      int q4 = (iq + rot) & 3;
      float4 re = *reinterpret_cast<const float4*>(&zr[pb + q4 * 4]);
      float4 im = *reinterpret_cast<const float4*>(&zi[pb + q4 * 4]);
      v[q4 * 4 + 0] = make_float2(re.x, im.x);
      v[q4 * 4 + 1] = make_float2(re.y, im.y);
      v[q4 * 4 + 2] = make_float2(re.z, im.z);
      v[q4 * 4 + 3] = make_float2(re.w, im.w);
    }
    reg16_fwd(v, tw);
    #pragma unroll
    for (int q = 0; q < 16; ++q) outp[base + q] = make_float2(v[q].x * inv, v[q].y * inv);
  }
}

// ---------------------------------------------------------------------------
// FFT convolution, two batches per block packed as real/imag. 512 threads.
// ---------------------------------------------------------------------------
__global__ __launch_bounds__(512, 4) void fft_conv(const float* __restrict__ x,
                                                   const float2* __restrict__ Hspec,
                                                   const float2* __restrict__ tw,
                                                   float* __restrict__ y) {
  extern __shared__ float smem[];
  float* zr = smem;
  float* zi = smem + NFFT;
  const int c  = blockIdx.x % C_;
  const int pr = blockIdx.x / C_;
  const int b1 = 2 * pr, b2 = b1 + 1;
  const int tid = threadIdx.x;
  const float4* x1 = reinterpret_cast<const float4*>(x + ((size_t)b1 * C_ + c) * L_);
  const float4* x2 = reinterpret_cast<const float4*>(x + ((size_t)b2 * C_ + c) * L_);
  const float4 z4 = make_float4(0.f, 0.f, 0.f, 0.f);
  for (int i = tid; i < L_ / 4; i += 512) {
    int p = i * 4;
    *reinterpret_cast<float4*>(&zr[SWZ(p)]) = x1[i];
    *reinterpret_cast<float4*>(&zi[SWZ(p)]) = x2[i];
    *reinterpret_cast<float4*>(&zr[SWZ(p + L_)]) = z4;
    *reinterpret_cast<float4*>(&zi[SWZ(p + L_)]) = z4;
  }
  __syncthreads();
  stage8p<false>(zr, zi, tw, tid, 1024, 10, 1);
  stage8p<false>(zr, zi, tw, tid, 128, 7, 8);
  stage8p<false>(zr, zi, tw, tid, 16, 4, 64);

  const float2* Hc = Hspec + (size_t)c * NFFT;
  {
    const int base = tid * 16;
    const int pb = SWZ(base);
    const int rot = tid & 3;
    float2 v[16];
    #pragma unroll
    for (int iq = 0; iq < 4; ++iq) {
      int q4 = (iq + rot) & 3;
      float4 re = *reinterpret_cast<const float4*>(&zr[pb + q4 * 4]);
      float4 im = *reinterpret_cast<const float4*>(&zi[pb + q4 * 4]);
      v[q4 * 4 + 0] = make_float2(re.x, im.x);
      v[q4 * 4 + 1] = make_float2(re.y, im.y);
      v[q4 * 4 + 2] = make_float2(re.z, im.z);
      v[q4 * 4 + 3] = make_float2(re.w, im.w);
    }
    reg16_fwd(v, tw);
    #pragma unroll
    for (int q = 0; q < 16; ++q) v[q] = cmul(v[q], Hc[base + q]);
    reg16_inv(v, tw);
    #pragma unroll
    for (int iq = 0; iq < 4; ++iq) {
      int q4 = (iq + rot) & 3;
      float4 re = make_float4(v[q4 * 4 + 0].x, v[q4 * 4 + 1].x, v[q4 * 4 + 2].x, v[q4 * 4 + 3].x);
      float4 im = make_float4(v[q4 * 4 + 0].y, v[q4 * 4 + 1].y, v[q4 * 4 + 2].y, v[q4 * 4 + 3].y);
      *reinterpret_cast<float4*>(&zr[pb + q4 * 4]) = re;
      *reinterpret_cast<float4*>(&zi[pb + q4 * 4]) = im;
    }
  }
  __syncthreads();
  stage8p<true>(zr, zi, tw, tid, 16, 4, 64);
  stage8p<true>(zr, zi, tw, tid, 128, 7, 8);
  stage8p<true>(zr, zi, tw, tid, 1024, 10, 1);

  float4* y1 = reinterpret_cast<float4*>(y + ((size_t)b1 * C_ + c) * L_);
  float4* y2 = reinterpret_cast<float4*>(y + ((size_t)b2 * C_ + c) * L_);
  for (int i = tid; i < L_ / 4; i += 512) {
    int p = i * 4;
    y1[i] = *reinterpret_cast<const float4*>(&zr[SWZ(p)]);
    y2[i] = *reinterpret_cast<const float4*>(&zi[SWZ(p)]);
  }
}

// ---------------------------------------------------------------------------
// Pointwise 1x1 conv: out[b][o][l] = sum_c pw[o][c] * y[b][c][l]
// fp32 GEMM: 128x128 tile, BK=16, 256 threads, 2x2 blocks of 4x4 per thread,
// register-prefetch software pipeline. grid = (L/128, HID/128, B)
// NOTE: plain __launch_bounds__(256) — the (256,4) min-occupancy variant
// capped VGPRs at 64 and spilled the 64-float accumulator to scratch
// (WRITE_SIZE blew up to 3 GB/dispatch, dur 945us). acc must stay resident.
// ---------------------------------------------------------------------------
#define MT 128
#define NT 128
#define KT 16
#define LDT 132
__global__ __launch_bounds__(256) void pw_gemm(const float* __restrict__ y,
                                               const float* __restrict__ pw,
                                               float* __restrict__ out) {
  const int b  = blockIdx.z;
  const int m0 = blockIdx.y * MT;
  const int n0 = blockIdx.x * NT;
  __shared__ float As[KT][LDT];   // [k][m]
  __shared__ float Bs[KT][LDT];   // [k][n]
  const int tid = threadIdx.x;
  const int tx = tid & 15, ty = tid >> 4;
  const int arow = tid >> 2, ac4 = (tid & 3) << 2;   // + rep*64 rows
  const int brow = tid >> 5, bcc = (tid & 31) << 2;  // + rep*8 rows
  float acc[2][2][4][4] = {{{{0.f}}}};
  const float* yb = y + (size_t)b * C_ * L_;

  float4 pa[2], pbv[2];
  #pragma unroll
  for (int rep = 0; rep < 2; ++rep) {
    pa[rep]  = *reinterpret_cast<const float4*>(pw + (size_t)(m0 + arow + rep * 64) * C_ + ac4);
    pbv[rep] = *reinterpret_cast<const float4*>(yb + (size_t)(brow + rep * 8) * L_ + n0 + bcc);
  }
  for (int k0 = 0; k0 < C_; k0 += KT) {
    #pragma unroll
    for (int rep = 0; rep < 2; ++rep) {
      int row = arow + rep * 64;
      As[ac4 + 0][row] = pa[rep].x; As[ac4 + 1][row] = pa[rep].y;
      As[ac4 + 2][row] = pa[rep].z; As[ac4 + 3][row] = pa[rep].w;
      *reinterpret_cast<float4*>(&Bs[brow + rep * 8][bcc]) = pbv[rep];
    }
    __syncthreads();
    if (k0 + KT < C_) {
      #pragma unroll
      for (int rep = 0; rep < 2; ++rep) {
        pa[rep]  = *reinterpret_cast<const float4*>(pw + (size_t)(m0 + arow + rep * 64) * C_ + (k0 + KT) + ac4);
        pbv[rep] = *reinterpret_cast<const float4*>(yb + (size_t)(k0 + KT + brow + rep * 8) * L_ + n0 + bcc);
      }
    }
    #pragma unroll
    for (int kk = 0; kk < KT; ++kk) {
      float4 a0 = *reinterpret_cast<const float4*>(&As[kk][ty * 4]);
      float4 a1 = *reinterpret_cast<const float4*>(&As[kk][ty * 4 + 64]);
      float4 b0 = *reinterpret_cast<const float4*>(&Bs[kk][tx * 4]);
      float4 b1 = *reinterpret_cast<const float4*>(&Bs[kk][tx * 4 + 64]);
      float av[2][4] = {{a0.x, a0.y, a0.z, a0.w}, {a1.x, a1.y, a1.z, a1.w}};
      float bv[2][4] = {{b0.x, b0.y, b0.z, b0.w}, {b1.x, b1.y, b1.z, b1.w}};
      #pragma unroll
      for (int ri = 0; ri < 2; ++ri)
        #pragma unroll
        for (int rj = 0; rj < 2; ++rj)
          #pragma unroll
          for (int i = 0; i < 4; ++i)
            #pragma unroll
            for (int j = 0; j < 4; ++j)
              acc[ri][rj][i][j] = fmaf(av[ri][i], bv[rj][j], acc[ri][rj][i][j]);
    }
    __syncthreads();
  }
  #pragma unroll
  for (int ri = 0; ri < 2; ++ri)
    #pragma unroll
    for (int i = 0; i < 4; ++i) {
      int grow = m0 + ty * 4 + i + ri * 64;
      float* orow = out + ((size_t)b * HID_ + grow) * L_ + n0;
      #pragma unroll
      for (int rj = 0; rj < 2; ++rj) {
        float4 v = make_float4(acc[ri][rj][i][0], acc[ri][rj][i][1],
                               acc[ri][rj][i][2], acc[ri][rj][i][3]);
        *reinterpret_cast<float4*>(orow + tx * 4 + rj * 64) = v;
      }
    }
}

// ---------------------------------------------------------------------------
extern "C" void kernel_launch(void* const* d_in, const int* in_sizes, int n_in,
                              void* d_out, int out_size, void* d_ws, size_t ws_size,
                              hipStream_t stream) {
  (void)in_sizes; (void)n_in; (void)out_size; (void)ws_size;
  const float* x          = (const float*)d_in[0];
  const float* mask_mean  = (const float*)d_in[1];
  const float* mask_sigma = (const float*)d_in[2];
  const float* gfw        = (const float*)d_in[3];
  const float* gfb        = (const float*)d_in[4];
  const float* gg         = (const float*)d_in[5];
  const float* gmu        = (const float*)d_in[6];
  const float* lin_w      = (const float*)d_in[7];
  const float* lin_b      = (const float*)d_in[8];
  const float* out_w      = (const float*)d_in[9];
  const float* out_b      = (const float*)d_in[10];
  const float* pw_w       = (const float*)d_in[11];
  float* out = (float*)d_out;

  // workspace layout (16B-aligned):
  //   tw    : float2[NFFT]          65536 B
  //   mk    : float [C*K]         6291456 B
  //   Hspec : float2[C*NFFT]     25165824 B
  //   y     : float [B*C*L]     100663296 B   (total ~132.3 MB)
  char* ws = (char*)d_ws;
  float2* tw = (float2*)ws;
  float*  mk = (float*)(ws + 65536);
  float2* Hs = (float2*)(ws + 65536 + 6291456);
  float*  y  = (float*)(ws + 65536 + 6291456 + 25165824);

  gen_tw<<<NFFT / 256, 256, 0, stream>>>(tw);
  gen_mk<<<dim3(K_ / 256, 24), 256, 0, stream>>>(mask_mean, mask_sigma, gfw, gfb, gg, gmu,
                                                 lin_w, lin_b, out_w, out_b, mk);
  fft_h<<<C_, 512, 2 * NFFT * sizeof(float), stream>>>(mk, tw, Hs);
  fft_conv<<<(B_ / 2) * C_, 512, 2 * NFFT * sizeof(float), stream>>>(x, Hs, tw, y);
  pw_gemm<<<dim3(L_ / NT, HID_ / MT, B_), 256, 0, stream>>>(y, pw_w, out);
}